// Round 1
// baseline (1232.917 us; speedup 1.0000x reference)
//
#include <hip/hip_runtime.h>
#include <hip/hip_fp16.h>
#include <cstdint>

#define D 128
#define BLK 256
#define NPB 32   // nodes per block in k_node

constexpr float MINN   = 1e-15f;
constexpr float ATCLIP = 1.0f - 1e-7f;
constexpr float BALLEPS = 4e-3f;

__device__ __forceinline__ float red32(float v) {
    v += __shfl_xor(v, 1);
    v += __shfl_xor(v, 2);
    v += __shfl_xor(v, 4);
    v += __shfl_xor(v, 8);
    v += __shfl_xor(v, 16);
    return v;
}

__device__ __forceinline__ float artanh_(float x) {
    x = fminf(fmaxf(x, -ATCLIP), ATCLIP);
    return atanhf(x);
}

// Kernel 1: per-node  h_t = logmap0( mobius_add( mobius_matvec(W,x), expmap0(b) ) )
// writes h_t into both `ht` (gather source) and `agg` (accumulator init).
__global__ __launch_bounds__(BLK) void k_node(
    const float* __restrict__ x, const float* __restrict__ W,
    const float* __restrict__ b, float* __restrict__ ht,
    float* __restrict__ agg, int N)
{
    // WT2[i][jp] = half2( W[jp][i], W[jp+64][i] ), jp in [0,64), stride 65 -> conflict-free
    __shared__ __half2 WT2[D * 65];
    __shared__ float   xs[NPB * D];
    __shared__ float   ps[D];           // p = expmap0(b)

    const int t  = threadIdx.x;
    const int tx = t & 31;
    const int ty = t >> 5;              // 0..7

    // ---- stage W transposed as fp16 pairs (coalesced global reads, conflict-free LDS writes)
    for (int it = 0; it < 32; ++it) {
        int lin = it * BLK + t;         // 8192 pairs
        int i   = lin & 127;
        int jp  = lin >> 7;             // 0..63
        float w0 = W[jp * D + i];
        float w1 = W[(jp + 64) * D + i];
        WT2[i * 65 + jp] = __floats2half2_rn(w0, w1);
    }

    // ---- stage x tile (float4, coalesced)
    const int node0 = blockIdx.x * NPB;
    float4* xs4 = (float4*)xs;
    for (int it = 0; it < 4; ++it) {
        int lin4 = it * BLK + t;        // 1024 float4 = 32 nodes * 32
        int n    = lin4 >> 5;
        int gn   = node0 + n;
        float4 v = make_float4(0.f, 0.f, 0.f, 0.f);
        if (gn < N) v = ((const float4*)x)[(size_t)gn * (D / 4) + (lin4 & 31)];
        xs4[lin4] = v;
    }

    // ---- p = expmap0(b): uniform scalar loop (s_load chain), every thread redundantly
    float bn2 = 0.f;
    for (int k = 0; k < D; ++k) { float v = b[k]; bn2 = fmaf(v, v, bn2); }
    float bnc    = fmaxf(sqrtf(bn2), MINN);
    float bscale = tanhf(bnc) / bnc;
    if (t < D) ps[t] = b[t] * bscale;
    const float y2 = bscale * bscale * bn2;   // ||p||^2
    __syncthreads();

    // ---- matvec: acc[r][m] = mx[node ty*4+r][tx + 32*m]
    float acc[4][4];
#pragma unroll
    for (int r = 0; r < 4; ++r)
#pragma unroll
        for (int m = 0; m < 4; ++m) acc[r][m] = 0.f;

    for (int i4 = 0; i4 < D; i4 += 4) {
        float4 xv[4];
#pragma unroll
        for (int r = 0; r < 4; ++r)
            xv[r] = *(const float4*)&xs[(ty * 4 + r) * D + i4];   // LDS broadcast
#pragma unroll
        for (int k = 0; k < 4; ++k) {
            const int i = i4 + k;
            float2 a0 = __half22float2(WT2[i * 65 + tx]);        // (j=tx,    j=tx+64)
            float2 a1 = __half22float2(WT2[i * 65 + tx + 32]);   // (j=tx+32, j=tx+96)
#pragma unroll
            for (int r = 0; r < 4; ++r) {
                float xk = (k == 0) ? xv[r].x : (k == 1) ? xv[r].y : (k == 2) ? xv[r].z : xv[r].w;
                acc[r][0] = fmaf(xk, a0.x, acc[r][0]);
                acc[r][1] = fmaf(xk, a1.x, acc[r][1]);
                acc[r][2] = fmaf(xk, a0.y, acc[r][2]);
                acc[r][3] = fmaf(xk, a1.y, acc[r][3]);
            }
        }
    }

    // ---- per-node epilogue
#pragma unroll
    for (int r = 0; r < 4; ++r) {
        const int n  = ty * 4 + r;
        const int gn = node0 + n;

        float px = 0.f, pm = 0.f, pd = 0.f;
#pragma unroll
        for (int m = 0; m < 4; ++m) {
            float xe = xs[n * D + tx + 32 * m];
            px = fmaf(xe, xe, px);
            pm = fmaf(acc[r][m], acc[r][m], pm);
            pd = fmaf(acc[r][m], ps[tx + 32 * m], pd);
        }
        float xn2  = red32(px);     // ||x||^2
        float mxn2 = red32(pm);     // ||mx||^2
        float mdp  = red32(pd);     // <mx, p>

        // mobius_matvec scale
        float xn      = fmaxf(sqrtf(xn2), MINN);
        float mxn_raw = sqrtf(mxn2);
        float mxn     = fmaxf(mxn_raw, MINN);
        float alpha   = tanhf(mxn / xn * artanh_(xn)) / mxn;
        if (mxn_raw <= 1e-10f) alpha = 0.f;   // zero-row guard

        // mobius_add(res = alpha*mx, p)
        float x2  = alpha * alpha * mxn2;
        float xy  = alpha * mdp;
        float den = fmaxf(fmaf(x2, y2, 1.f + 2.f * xy), MINN);
        float ca  = (1.f + 2.f * xy + y2) * alpha / den;
        float cb  = (1.f - x2) / den;

        float hh[4]; float ph = 0.f;
#pragma unroll
        for (int m = 0; m < 4; ++m) {
            hh[m] = ca * acc[r][m] + cb * ps[tx + 32 * m];
            ph = fmaf(hh[m], hh[m], ph);
        }
        float hn2 = red32(ph);
        float hn  = fmaxf(sqrtf(hn2), MINN);
        float lsc = artanh_(hn) / hn;      // logmap0 scale

        if (gn < N) {
#pragma unroll
            for (int m = 0; m < 4; ++m) {
                float o = lsc * hh[m];
                size_t idx = (size_t)gn * D + tx + 32 * m;
                ht[idx]  = o;
                agg[idx] = o;
            }
        }
    }
}

// Kernel 2: agg[dst] += h_t[src] * w   (32 lanes per edge, hw fp32 atomics)
__global__ __launch_bounds__(BLK) void k_edge(
    const int* __restrict__ ei, const float* __restrict__ ew,
    const float* __restrict__ ht, float* __restrict__ agg, int E)
{
    int tid = blockIdx.x * BLK + threadIdx.x;
    int e   = tid >> 5;
    if (e >= E) return;
    int c   = tid & 31;
    int src = ei[e];
    int dst = ei[E + e];
    float w = ew[e];
    float4 m = ((const float4*)(ht + (size_t)src * D))[c];
    float* base = agg + (size_t)dst * D + c * 4;
    unsafeAtomicAdd(base + 0, m.x * w);
    unsafeAtomicAdd(base + 1, m.y * w);
    unsafeAtomicAdd(base + 2, m.z * w);
    unsafeAtomicAdd(base + 3, m.w * w);
}

// Kernel 3: out = project( expmap0( prelu( logmap0( expmap0( agg ) ) ) ) )
__global__ __launch_bounds__(BLK) void k_final(
    const float* __restrict__ agg, const float* __restrict__ a_in,
    float* __restrict__ out, int N)
{
    int tid = blockIdx.x * BLK + threadIdx.x;
    int n   = tid >> 5;
    if (n >= N) return;
    int c   = tid & 31;
    float a = a_in[0];

    float4 g = ((const float4*)(agg + (size_t)n * D))[c];
    float pn = fmaf(g.x, g.x, fmaf(g.y, g.y, fmaf(g.z, g.z, g.w * g.w)));
    float n2 = red32(pn);

    float nc = fmaxf(sqrtf(n2), MINN);       // _norm(agg)
    float tt = tanhf(nc);                    // ||expmap0(agg)||
    float ny = fmaxf(tt, MINN);
    float sc = (artanh_(ny) / ny) * (tt / nc);   // logmap0(expmap0(.)) scale

    float v0 = sc * g.x; v0 = (v0 >= 0.f) ? v0 : a * v0;
    float v1 = sc * g.y; v1 = (v1 >= 0.f) ? v1 : a * v1;
    float v2 = sc * g.z; v2 = (v2 >= 0.f) ? v2 : a * v2;
    float v3 = sc * g.w; v3 = (v3 >= 0.f) ? v3 : a * v3;

    float pv = fmaf(v0, v0, fmaf(v1, v1, fmaf(v2, v2, v3 * v3)));
    float m2 = red32(pv);
    float rc = fmaxf(sqrtf(m2), MINN);
    float te = tanhf(rc);
    float es = te / rc;                      // expmap0 scale
    float en = fmaxf(te, MINN);              // _norm(expmap0 result)
    const float maxn = 1.0f - BALLEPS;
    float fsc = (en > maxn) ? (es * maxn / en) : es;   // project

    float4 o = make_float4(fsc * v0, fsc * v1, fsc * v2, fsc * v3);
    ((float4*)(out + (size_t)n * D))[c] = o;
}

extern "C" void kernel_launch(void* const* d_in, const int* in_sizes, int n_in,
                              void* d_out, int out_size, void* d_ws, size_t ws_size,
                              hipStream_t stream)
{
    const float* x  = (const float*)d_in[0];
    const int*   ei = (const int*)  d_in[1];
    const float* ew = (const float*)d_in[2];
    const float* W  = (const float*)d_in[3];
    const float* b  = (const float*)d_in[4];
    const float* a  = (const float*)d_in[5];
    float* out = (float*)d_out;     // holds h_t between k_node and k_final
    float* agg = (float*)d_ws;      // N*D floats of scratch

    const int N = in_sizes[0] / D;
    const int E = in_sizes[1] / 2;

    int nb1 = (N + NPB - 1) / NPB;
    k_node<<<nb1, BLK, 0, stream>>>(x, W, b, out, agg, N);

    long long te = (long long)E * 32;
    int nb2 = (int)((te + BLK - 1) / BLK);
    k_edge<<<nb2, BLK, 0, stream>>>(ei, ew, out, agg, E);

    long long tf = (long long)N * 32;
    int nb3 = (int)((tf + BLK - 1) / BLK);
    k_final<<<nb3, BLK, 0, stream>>>(agg, a, out, N);
}

// Round 2
// 308.827 us; speedup vs baseline: 3.9923x; 3.9923x over previous
//
#include <hip/hip_runtime.h>
#include <hip/hip_fp16.h>
#include <cstdint>

#define D 128
#define BLK 256
#define NPB 32   // nodes per block in k_node

constexpr float MINN    = 1e-15f;
constexpr float ATCLIP  = 1.0f - 1e-7f;
constexpr float BALLEPS = 4e-3f;

union H2U { __half2 h; unsigned u; };

__device__ __forceinline__ float red32(float v) {
    v += __shfl_xor(v, 1);
    v += __shfl_xor(v, 2);
    v += __shfl_xor(v, 4);
    v += __shfl_xor(v, 8);
    v += __shfl_xor(v, 16);
    return v;
}

__device__ __forceinline__ float artanh_(float x) {
    x = fminf(fmaxf(x, -ATCLIP), ATCLIP);
    return atanhf(x);
}

__device__ __forceinline__ float2 h2f(unsigned bits) {
    H2U u; u.u = bits;
    return __half22float2(u.h);
}

// epilogue: out = project( expmap0( prelu( logmap0( expmap0( g ) ) ) ) )
// g = this lane's 4 consecutive components (d = 4*tx .. 4*tx+3); red32 spans the node.
__device__ __forceinline__ float4 epilogue(float4 g, float a) {
    float pn = fmaf(g.x, g.x, fmaf(g.y, g.y, fmaf(g.z, g.z, g.w * g.w)));
    float n2 = red32(pn);
    float nc = fmaxf(sqrtf(n2), MINN);        // _norm(agg)
    float tt = tanhf(nc);                     // ||expmap0(agg)||
    float ny = fmaxf(tt, MINN);
    float sc = (artanh_(ny) / ny) * (tt / nc);  // logmap0(expmap0(.)) scale

    float v0 = sc * g.x; v0 = (v0 >= 0.f) ? v0 : a * v0;
    float v1 = sc * g.y; v1 = (v1 >= 0.f) ? v1 : a * v1;
    float v2 = sc * g.z; v2 = (v2 >= 0.f) ? v2 : a * v2;
    float v3 = sc * g.w; v3 = (v3 >= 0.f) ? v3 : a * v3;

    float pv = fmaf(v0, v0, fmaf(v1, v1, fmaf(v2, v2, v3 * v3)));
    float m2 = red32(pv);
    float rc = fmaxf(sqrtf(m2), MINN);
    float te = tanhf(rc);
    float es = te / rc;                       // expmap0 scale
    float en = fmaxf(te, MINN);
    const float maxn = 1.0f - BALLEPS;
    float fsc = (en > maxn) ? (es * maxn / en) : es;   // project
    return make_float4(fsc * v0, fsc * v1, fsc * v2, fsc * v3);
}

// ---------------------------------------------------------------------------
// Kernel 1: h_t = logmap0( mobius_add( mobius_matvec(W,x), expmap0(b) ) )
// written as fp16 (uint2 = 4 halves/lane, lane tx owns dims 4tx..4tx+3)
// ---------------------------------------------------------------------------
__global__ __launch_bounds__(BLK) void k_node(
    const float* __restrict__ x, const float* __restrict__ W,
    const float* __restrict__ b, uint2* __restrict__ ht, int N)
{
    // WLO[i*33+q] = half2(W[4q+0][i], W[4q+1][i]); WHI: rows 4q+2, 4q+3
    __shared__ __half2 WLO[D * 33];
    __shared__ __half2 WHI[D * 33];
    __shared__ float   xs[NPB * D];
    __shared__ float   ps[D];           // p = expmap0(b)

    const int t  = threadIdx.x;
    const int tx = t & 31;
    const int ty = t >> 5;              // 0..7

    // ---- stage W transposed as fp16 pairs (coalesced global, conflict-free-ish LDS)
    for (int it = 0; it < 16; ++it) {
        int lin = it * BLK + t;         // 4096
        int i   = lin & 127;
        int q   = lin >> 7;             // 0..31
        float w0 = W[(4 * q + 0) * D + i];
        float w1 = W[(4 * q + 1) * D + i];
        float w2 = W[(4 * q + 2) * D + i];
        float w3 = W[(4 * q + 3) * D + i];
        WLO[i * 33 + q] = __floats2half2_rn(w0, w1);
        WHI[i * 33 + q] = __floats2half2_rn(w2, w3);
    }

    // ---- stage x tile
    const int node0 = blockIdx.x * NPB;
    float4* xs4 = (float4*)xs;
    for (int it = 0; it < 4; ++it) {
        int lin4 = it * BLK + t;        // 1024 float4
        int n    = lin4 >> 5;
        int gn   = node0 + n;
        float4 v = make_float4(0.f, 0.f, 0.f, 0.f);
        if (gn < N) v = ((const float4*)x)[(size_t)gn * 32 + (lin4 & 31)];
        xs4[lin4] = v;
    }

    // ---- p = expmap0(b): uniform scalar loop
    float bn2 = 0.f;
    for (int k = 0; k < D; ++k) { float v = b[k]; bn2 = fmaf(v, v, bn2); }
    float bnc    = fmaxf(sqrtf(bn2), MINN);
    float bscale = tanhf(bnc) / bnc;
    if (t < D) ps[t] = b[t] * bscale;
    const float y2 = bscale * bscale * bn2;   // ||p||^2
    __syncthreads();

    // ---- matvec: acc[r][m] = mx[node ty*4+r][4*tx+m]
    float acc[4][4];
#pragma unroll
    for (int r = 0; r < 4; ++r)
#pragma unroll
        for (int m = 0; m < 4; ++m) acc[r][m] = 0.f;

    for (int i4 = 0; i4 < D; i4 += 4) {
        float4 xv[4];
#pragma unroll
        for (int r = 0; r < 4; ++r)
            xv[r] = *(const float4*)&xs[(ty * 4 + r) * D + i4];   // LDS broadcast
#pragma unroll
        for (int k = 0; k < 4; ++k) {
            const int i = i4 + k;
            float2 f0 = __half22float2(WLO[i * 33 + tx]);  // rows 4tx, 4tx+1
            float2 f1 = __half22float2(WHI[i * 33 + tx]);  // rows 4tx+2, 4tx+3
#pragma unroll
            for (int r = 0; r < 4; ++r) {
                float xk = (k == 0) ? xv[r].x : (k == 1) ? xv[r].y : (k == 2) ? xv[r].z : xv[r].w;
                acc[r][0] = fmaf(xk, f0.x, acc[r][0]);
                acc[r][1] = fmaf(xk, f0.y, acc[r][1]);
                acc[r][2] = fmaf(xk, f1.x, acc[r][2]);
                acc[r][3] = fmaf(xk, f1.y, acc[r][3]);
            }
        }
    }

    // ---- per-node epilogue
    const float4* ps4 = (const float4*)ps;
#pragma unroll
    for (int r = 0; r < 4; ++r) {
        const int n  = ty * 4 + r;
        const int gn = node0 + n;

        float4 xq = xs4[n * 32 + tx];        // x dims 4tx..4tx+3
        float4 pq = ps4[tx];                 // p dims 4tx..4tx+3

        float px = fmaf(xq.x, xq.x, fmaf(xq.y, xq.y, fmaf(xq.z, xq.z, xq.w * xq.w)));
        float pm = 0.f, pd = 0.f;
        float pe[4] = { pq.x, pq.y, pq.z, pq.w };
#pragma unroll
        for (int m = 0; m < 4; ++m) {
            pm = fmaf(acc[r][m], acc[r][m], pm);
            pd = fmaf(acc[r][m], pe[m], pd);
        }
        float xn2  = red32(px);     // ||x||^2
        float mxn2 = red32(pm);     // ||mx||^2
        float mdp  = red32(pd);     // <mx, p>

        float xn      = fmaxf(sqrtf(xn2), MINN);
        float mxn_raw = sqrtf(mxn2);
        float mxn     = fmaxf(mxn_raw, MINN);
        float alpha   = tanhf(mxn / xn * artanh_(xn)) / mxn;
        if (mxn_raw <= 1e-10f) alpha = 0.f;   // zero-row guard

        // mobius_add(res = alpha*mx, p)
        float x2  = alpha * alpha * mxn2;
        float xy  = alpha * mdp;
        float den = fmaxf(fmaf(x2, y2, 1.f + 2.f * xy), MINN);
        float ca  = (1.f + 2.f * xy + y2) * alpha / den;
        float cb  = (1.f - x2) / den;

        float hh[4]; float ph = 0.f;
#pragma unroll
        for (int m = 0; m < 4; ++m) {
            hh[m] = ca * acc[r][m] + cb * pe[m];
            ph = fmaf(hh[m], hh[m], ph);
        }
        float hn2 = red32(ph);
        float hn  = fmaxf(sqrtf(hn2), MINN);
        float lsc = artanh_(hn) / hn;      // logmap0 scale

        if (gn < N) {
            H2U lo, hi;
            lo.h = __floats2half2_rn(lsc * hh[0], lsc * hh[1]);
            hi.h = __floats2half2_rn(lsc * hh[2], lsc * hh[3]);
            uint2 o; o.x = lo.u; o.y = hi.u;
            ht[(size_t)gn * 32 + tx] = o;
        }
    }
}

// ---------------------------------------------------------------------------
// CSR build: zero -> hist -> scan(3) -> scatter
// ---------------------------------------------------------------------------
__global__ void k_zero(int* __restrict__ c, int n) {
    int i = blockIdx.x * 256 + threadIdx.x;
    if (i < n) c[i] = 0;
}

__global__ void k_hist(const int* __restrict__ ei, int* __restrict__ cnt, int E) {
    int e = blockIdx.x * 256 + threadIdx.x;
    if (e < E) atomicAdd(&cnt[ei[E + e]], 1);
}

// chunk = 1024 per block; thread t handles elements [4t, 4t+4)
__global__ __launch_bounds__(256) void k_scan1(
    const int* __restrict__ cnt, int* __restrict__ ptr,
    int* __restrict__ part, int N)
{
    __shared__ int s[256];
    int t = threadIdx.x;
    int base = blockIdx.x * 1024 + t * 4;
    int v0 = 0, v1 = 0, v2 = 0, v3 = 0;
    if (base + 3 < N) {
        int4 q = *(const int4*)&cnt[base];
        v0 = q.x; v1 = q.y; v2 = q.z; v3 = q.w;
    } else {
        if (base + 0 < N) v0 = cnt[base + 0];
        if (base + 1 < N) v1 = cnt[base + 1];
        if (base + 2 < N) v2 = cnt[base + 2];
        if (base + 3 < N) v3 = cnt[base + 3];
    }
    int sum = v0 + v1 + v2 + v3;
    s[t] = sum;
    __syncthreads();
    for (int off = 1; off < 256; off <<= 1) {
        int xv = (t >= off) ? s[t - off] : 0;
        __syncthreads();
        s[t] += xv;
        __syncthreads();
    }
    int excl = s[t] - sum;
    if (t == 255) part[blockIdx.x] = s[255];
    int r = excl;
    if (base + 0 < N) ptr[base + 0] = r; r += v0;
    if (base + 1 < N) ptr[base + 1] = r; r += v1;
    if (base + 2 < N) ptr[base + 2] = r; r += v2;
    if (base + 3 < N) ptr[base + 3] = r;
}

__global__ __launch_bounds__(256) void k_scan2(int* __restrict__ part, int nc) {
    __shared__ int s[256];
    int t = threadIdx.x;
    int v = (t < nc) ? part[t] : 0;
    s[t] = v;
    __syncthreads();
    for (int off = 1; off < 256; off <<= 1) {
        int xv = (t >= off) ? s[t - off] : 0;
        __syncthreads();
        s[t] += xv;
        __syncthreads();
    }
    if (t < nc) part[t] = s[t] - v;   // exclusive
}

__global__ void k_scan3(int* __restrict__ ptr, const int* __restrict__ part, int N) {
    int i = blockIdx.x * 256 + threadIdx.x;
    if (i < N) ptr[i] += part[i >> 10];
}

// scatter: ptr is consumed as cursor; afterwards ptr[n] == end(n)
__global__ void k_scatter(const int* __restrict__ ei, const float* __restrict__ ew,
                          int* __restrict__ ptr, int2* __restrict__ sorted, int E)
{
    int e = blockIdx.x * 256 + threadIdx.x;
    if (e >= E) return;
    int src = ei[e];
    int dst = ei[E + e];
    float w = ew[e];
    int pos = atomicAdd(&ptr[dst], 1);
    sorted[pos] = make_int2(src, __float_as_int(w));
}

// ---------------------------------------------------------------------------
// Kernel 3 (fused): per-node register aggregation over CSR + full epilogue
// ---------------------------------------------------------------------------
__global__ __launch_bounds__(256) void k_agg_final(
    const uint2* __restrict__ ht, const int* __restrict__ ptr,
    const int2* __restrict__ sorted, const float* __restrict__ a_in,
    float* __restrict__ out, int N)
{
    int t  = threadIdx.x;
    int tx = t & 31;
    int ty = t >> 5;
    int n  = blockIdx.x * 8 + ty;
    if (n >= N) return;
    float a = a_in[0];

    uint2 own = ht[(size_t)n * 32 + tx];
    float2 lo = h2f(own.x), hi = h2f(own.y);
    float4 acc = make_float4(lo.x, lo.y, hi.x, hi.y);   // agg starts at h_t[n]

    int start = (n > 0) ? ptr[n - 1] : 0;
    int end   = ptr[n];

    for (int base = start; base < end; base += 32) {
        int2 d = make_int2(0, 0);
        if (base + tx < end) d = sorted[base + tx];
        int lim = min(32, end - base);
        for (int j = 0; j < lim; ++j) {
            int   sj = __shfl(d.x, j, 32);
            float wj = __shfl(__int_as_float(d.y), j, 32);
            uint2 g  = ht[(size_t)sj * 32 + tx];
            float2 gl = h2f(g.x), gh = h2f(g.y);
            acc.x = fmaf(wj, gl.x, acc.x);
            acc.y = fmaf(wj, gl.y, acc.y);
            acc.z = fmaf(wj, gh.x, acc.z);
            acc.w = fmaf(wj, gh.y, acc.w);
        }
    }

    float4 o = epilogue(acc, a);
    ((float4*)out)[(size_t)n * 32 + tx] = o;
}

// ---------------------------------------------------------------------------
extern "C" void kernel_launch(void* const* d_in, const int* in_sizes, int n_in,
                              void* d_out, int out_size, void* d_ws, size_t ws_size,
                              hipStream_t stream)
{
    const float* x  = (const float*)d_in[0];
    const int*   ei = (const int*)  d_in[1];
    const float* ew = (const float*)d_in[2];
    const float* W  = (const float*)d_in[3];
    const float* b  = (const float*)d_in[4];
    const float* a  = (const float*)d_in[5];
    float* out = (float*)d_out;

    const int N = in_sizes[0] / D;
    const int E = in_sizes[1] / 2;

    // workspace carve-up (~31.2 MB)
    char* ws = (char*)d_ws;
    size_t HT_B   = (size_t)N * D * 2;          // fp16 h_t
    uint2* ht     = (uint2*)ws;
    int*   cnt    = (int*)(ws + HT_B);
    int*   ptr    = (int*)(ws + HT_B + (size_t)N * 4);
    int*   part   = (int*)(ws + HT_B + (size_t)N * 8);
    int2*  sorted = (int2*)(ws + HT_B + (size_t)N * 8 + 1024);

    int nc = (N + 1023) / 1024;   // scan chunks

    k_node<<<(N + NPB - 1) / NPB, BLK, 0, stream>>>(x, W, b, ht, N);

    k_zero<<<(N + 255) / 256, 256, 0, stream>>>(cnt, N);
    k_hist<<<(E + 255) / 256, 256, 0, stream>>>(ei, cnt, E);
    k_scan1<<<nc, 256, 0, stream>>>(cnt, ptr, part, N);
    k_scan2<<<1, 256, 0, stream>>>(part, nc);
    k_scan3<<<(N + 255) / 256, 256, 0, stream>>>(ptr, part, N);
    k_scatter<<<(E + 255) / 256, 256, 0, stream>>>(ei, ew, ptr, sorted, E);

    k_agg_final<<<(N + 7) / 8, 256, 0, stream>>>(ht, ptr, sorted, a, out, N);
}

// Round 3
// 249.005 us; speedup vs baseline: 4.9514x; 1.2402x over previous
//
#include <hip/hip_runtime.h>
#include <hip/hip_fp16.h>
#include <cstdint>

#define D 128
#define BLK 256

constexpr float MINN    = 1e-15f;
constexpr float ATCLIP  = 1.0f - 1e-7f;
constexpr float BALLEPS = 4e-3f;

typedef _Float16 f16x8 __attribute__((ext_vector_type(8)));
typedef float    f32x4 __attribute__((ext_vector_type(4)));

union H4 { _Float16 h[4]; uint2 u2; };
union H2U { __half2 h; unsigned u; };

__device__ __forceinline__ float red32(float v) {
    v += __shfl_xor(v, 1);
    v += __shfl_xor(v, 2);
    v += __shfl_xor(v, 4);
    v += __shfl_xor(v, 8);
    v += __shfl_xor(v, 16);
    return v;
}

__device__ __forceinline__ float artanh_(float x) {
    x = fminf(fmaxf(x, -ATCLIP), ATCLIP);
    return atanhf(x);
}

__device__ __forceinline__ float2 h2f(unsigned bits) {
    H2U u; u.u = bits;
    return __half22float2(u.h);
}

// ---------------------------------------------------------------------------
// Kernel 1 (MFMA): h_t = logmap0( mobius_add( mobius_matvec(W,x), expmap0(b) ) )
// 64 nodes/block, 4 waves; wave w owns nodes w*16..w*16+15 (16-col MFMA tile).
// ht written fp16: ht[node*32 + col] packs dims 4col..4col+3.
// ---------------------------------------------------------------------------
__global__ __launch_bounds__(BLK) void k_node_mfma(
    const float* __restrict__ x, const float* __restrict__ W,
    const float* __restrict__ b, uint2* __restrict__ ht, int N)
{
    __shared__ _Float16 Ws[D * 136];    // 34816 B, row-major padded
    __shared__ _Float16 xs[64 * 136];   // 17408 B (later overlaid by out-staging)
    __shared__ float    ps[D];          // p = expmap0(b)
    __shared__ float    xn2s[64];       // exact fp32 ||x||^2 per node

    const int t     = threadIdx.x;
    const int node0 = blockIdx.x * 64;

    // ---- stage W fp32 -> fp16 LDS (coalesced float4 reads, 8B LDS writes)
    for (int it = 0; it < 16; ++it) {
        int lin = it * BLK + t;         // 4096 float4
        int row = lin >> 5;
        int c4  = (lin & 31) * 4;
        float4 v = ((const float4*)W)[lin];
        H4 u;
        u.h[0] = (_Float16)v.x; u.h[1] = (_Float16)v.y;
        u.h[2] = (_Float16)v.z; u.h[3] = (_Float16)v.w;
        *(uint2*)&Ws[row * 136 + c4] = u.u2;
    }

    // ---- stage x fp32 -> fp16 LDS + exact fp32 norms
    for (int it = 0; it < 8; ++it) {
        int lin  = it * BLK + t;        // 2048 float4
        int node = lin >> 5;
        int c4   = (lin & 31) * 4;
        int gn   = node0 + node;
        float4 v = make_float4(0.f, 0.f, 0.f, 0.f);
        if (gn < N) v = ((const float4*)x)[(size_t)gn * 32 + (lin & 31)];
        H4 u;
        u.h[0] = (_Float16)v.x; u.h[1] = (_Float16)v.y;
        u.h[2] = (_Float16)v.z; u.h[3] = (_Float16)v.w;
        *(uint2*)&xs[node * 136 + c4] = u.u2;
        float s = fmaf(v.x, v.x, fmaf(v.y, v.y, fmaf(v.z, v.z, v.w * v.w)));
        s = red32(s);                   // sums the 32-lane subgroup = one node
        if ((t & 31) == 0) xn2s[node] = s;
    }

    // ---- p = expmap0(b): uniform scalar loop
    float bn2 = 0.f;
    for (int k = 0; k < D; ++k) { float v = b[k]; bn2 = fmaf(v, v, bn2); }
    float bnc    = fmaxf(sqrtf(bn2), MINN);
    float bscale = tanhf(bnc) / bnc;
    if (t < D) ps[t] = b[t] * bscale;
    const float y2 = bscale * bscale * bn2;   // ||p||^2
    __syncthreads();

    // ---- MFMA: mx[128 out][16 nodes] per wave
    const int lane = t & 63;
    const int w    = t >> 6;
    const int c    = lane & 15;     // node within wave-tile / W row within m-tile
    const int g    = lane >> 4;     // quad

    f32x4 Cf[8];
#pragma unroll
    for (int mt = 0; mt < 8; ++mt) Cf[mt] = (f32x4){0.f, 0.f, 0.f, 0.f};

    const _Float16* xbase = &xs[(w * 16 + c) * 136];
#pragma unroll
    for (int s = 0; s < 4; ++s) {
        f16x8 Bf = *(const f16x8*)&xbase[s * 32 + g * 8];
#pragma unroll
        for (int mt = 0; mt < 8; ++mt) {
            f16x8 Af = *(const f16x8*)&Ws[(mt * 16 + c) * 136 + s * 32 + g * 8];
            Cf[mt] = __builtin_amdgcn_mfma_f32_16x16x32_f16(Af, Bf, Cf[mt], 0, 0, 0);
        }
    }
    // lane holds mx[mt*16 + g*4 + r][node0 + w*16 + c] in Cf[mt][r]

    // ---- per-node epilogue (node = w*16 + c; 4 lanes per node via quads)
    float pm = 0.f, pd = 0.f;
    const float4* ps4 = (const float4*)ps;
#pragma unroll
    for (int mt = 0; mt < 8; ++mt) {
        float4 pv = ps4[mt * 4 + g];
        pm = fmaf(Cf[mt][0], Cf[mt][0], pm);
        pm = fmaf(Cf[mt][1], Cf[mt][1], pm);
        pm = fmaf(Cf[mt][2], Cf[mt][2], pm);
        pm = fmaf(Cf[mt][3], Cf[mt][3], pm);
        pd = fmaf(Cf[mt][0], pv.x, pd);
        pd = fmaf(Cf[mt][1], pv.y, pd);
        pd = fmaf(Cf[mt][2], pv.z, pd);
        pd = fmaf(Cf[mt][3], pv.w, pd);
    }
    pm += __shfl_xor(pm, 16); pm += __shfl_xor(pm, 32);   // ||mx||^2
    pd += __shfl_xor(pd, 16); pd += __shfl_xor(pd, 32);   // <mx, p>
    float xn2 = xn2s[w * 16 + c];

    float xn      = fmaxf(sqrtf(xn2), MINN);
    float mxn_raw = sqrtf(pm);
    float mxn     = fmaxf(mxn_raw, MINN);
    float alpha   = tanhf(mxn / xn * artanh_(xn)) / mxn;
    if (mxn_raw <= 1e-10f) alpha = 0.f;     // zero-row guard

    float x2  = alpha * alpha * pm;
    float xy  = alpha * pd;
    float den = fmaxf(fmaf(x2, y2, 1.f + 2.f * xy), MINN);
    float ca  = (1.f + 2.f * xy + y2) * alpha / den;
    float cb  = (1.f - x2) / den;

    // ||h||^2 analytically: h = ca*mx + cb*p
    float hn2 = ca * ca * pm + 2.f * ca * cb * pd + cb * cb * y2;
    float hn  = fmaxf(sqrtf(hn2), MINN);
    float lsc = artanh_(hn) / hn;
    float s1  = lsc * ca, s2 = lsc * cb;

    // ---- pack to fp16 via LDS transpose (overlay own wave's dead x region)
    uint2* lout = (uint2*)((char*)xs + (size_t)w * 16 * 136 * 2);
#pragma unroll
    for (int mt = 0; mt < 8; ++mt) {
        float4 pv = ps4[mt * 4 + g];
        H4 u;
        u.h[0] = (_Float16)fmaf(s1, Cf[mt][0], s2 * pv.x);
        u.h[1] = (_Float16)fmaf(s1, Cf[mt][1], s2 * pv.y);
        u.h[2] = (_Float16)fmaf(s1, Cf[mt][2], s2 * pv.z);
        u.h[3] = (_Float16)fmaf(s1, Cf[mt][3], s2 * pv.w);
        lout[c * 33 + mt * 4 + g] = u.u2;   // col = mt*4+g holds dims 4col..4col+3
    }
    __syncthreads();

    // ---- coalesced copy-out
    for (int it = 0; it < 8; ++it) {
        int lin  = it * BLK + t;        // 2048 uint2
        int node = lin >> 5;
        int col  = lin & 31;
        int gn   = node0 + node;
        if (gn < N) {
            const uint2* lsrc = (const uint2*)((const char*)xs + (size_t)(node >> 4) * 4352);
            ht[(size_t)gn * 32 + col] = lsrc[(node & 15) * 33 + col];
        }
    }
}

// ---------------------------------------------------------------------------
// CSR build: zero -> hist -> scan(3) -> scatter
// ---------------------------------------------------------------------------
__global__ void k_zero(int* __restrict__ c, int n) {
    int i = blockIdx.x * 256 + threadIdx.x;
    if (i < n) c[i] = 0;
}

__global__ void k_hist(const int* __restrict__ ei, int* __restrict__ cnt, int E) {
    int e = blockIdx.x * 256 + threadIdx.x;
    if (e < E) atomicAdd(&cnt[ei[E + e]], 1);
}

__global__ __launch_bounds__(256) void k_scan1(
    const int* __restrict__ cnt, int* __restrict__ ptr,
    int* __restrict__ part, int N)
{
    __shared__ int s[256];
    int t = threadIdx.x;
    int base = blockIdx.x * 1024 + t * 4;
    int v0 = 0, v1 = 0, v2 = 0, v3 = 0;
    if (base + 3 < N) {
        int4 q = *(const int4*)&cnt[base];
        v0 = q.x; v1 = q.y; v2 = q.z; v3 = q.w;
    } else {
        if (base + 0 < N) v0 = cnt[base + 0];
        if (base + 1 < N) v1 = cnt[base + 1];
        if (base + 2 < N) v2 = cnt[base + 2];
        if (base + 3 < N) v3 = cnt[base + 3];
    }
    int sum = v0 + v1 + v2 + v3;
    s[t] = sum;
    __syncthreads();
    for (int off = 1; off < 256; off <<= 1) {
        int xv = (t >= off) ? s[t - off] : 0;
        __syncthreads();
        s[t] += xv;
        __syncthreads();
    }
    int excl = s[t] - sum;
    if (t == 255) part[blockIdx.x] = s[255];
    int r = excl;
    if (base + 0 < N) ptr[base + 0] = r; r += v0;
    if (base + 1 < N) ptr[base + 1] = r; r += v1;
    if (base + 2 < N) ptr[base + 2] = r; r += v2;
    if (base + 3 < N) ptr[base + 3] = r;
}

__global__ __launch_bounds__(256) void k_scan2(int* __restrict__ part, int nc) {
    __shared__ int s[256];
    int t = threadIdx.x;
    int v = (t < nc) ? part[t] : 0;
    s[t] = v;
    __syncthreads();
    for (int off = 1; off < 256; off <<= 1) {
        int xv = (t >= off) ? s[t - off] : 0;
        __syncthreads();
        s[t] += xv;
        __syncthreads();
    }
    if (t < nc) part[t] = s[t] - v;   // exclusive
}

__global__ void k_scan3(int* __restrict__ ptr, const int* __restrict__ part, int N) {
    int i = blockIdx.x * 256 + threadIdx.x;
    if (i < N) ptr[i] += part[i >> 10];
}

__global__ void k_scatter(const int* __restrict__ ei, const float* __restrict__ ew,
                          int* __restrict__ ptr, int2* __restrict__ sorted, int E)
{
    int e = blockIdx.x * 256 + threadIdx.x;
    if (e >= E) return;
    int src = ei[e];
    int dst = ei[E + e];
    float w = ew[e];
    int pos = atomicAdd(&ptr[dst], 1);
    sorted[pos] = make_int2(src, __float_as_int(w));
}

// ---------------------------------------------------------------------------
// Fused aggregation + epilogue
// ---------------------------------------------------------------------------
__global__ __launch_bounds__(256) void k_agg_final(
    const uint2* __restrict__ ht, const int* __restrict__ ptr,
    const int2* __restrict__ sorted, const float* __restrict__ a_in,
    float* __restrict__ out, int N)
{
    int t  = threadIdx.x;
    int tx = t & 31;
    int ty = t >> 5;
    int n  = blockIdx.x * 8 + ty;
    if (n >= N) return;
    float a = a_in[0];

    uint2 own = ht[(size_t)n * 32 + tx];
    float2 lo = h2f(own.x), hi = h2f(own.y);
    float4 acc = make_float4(lo.x, lo.y, hi.x, hi.y);   // agg starts at h_t[n]

    int start = (n > 0) ? ptr[n - 1] : 0;
    int end   = ptr[n];

    for (int base = start; base < end; base += 32) {
        int2 d = make_int2(0, 0);
        if (base + tx < end) d = sorted[base + tx];
        int lim = min(32, end - base);
        for (int j = 0; j < lim; ++j) {
            int   sj = __shfl(d.x, j, 32);
            float wj = __shfl(__int_as_float(d.y), j, 32);
            uint2 gg = ht[(size_t)sj * 32 + tx];
            float2 gl = h2f(gg.x), gh = h2f(gg.y);
            acc.x = fmaf(wj, gl.x, acc.x);
            acc.y = fmaf(wj, gl.y, acc.y);
            acc.z = fmaf(wj, gh.x, acc.z);
            acc.w = fmaf(wj, gh.y, acc.w);
        }
    }

    // epilogue: project(expmap0(prelu(logmap0(expmap0(acc)))))
    float pn = fmaf(acc.x, acc.x, fmaf(acc.y, acc.y, fmaf(acc.z, acc.z, acc.w * acc.w)));
    float n2 = red32(pn);
    float ncl = fmaxf(sqrtf(n2), MINN);
    float tt  = tanhf(ncl);
    float ny  = fmaxf(tt, MINN);
    float sc  = (artanh_(ny) / ny) * (tt / ncl);

    float v0 = sc * acc.x; v0 = (v0 >= 0.f) ? v0 : a * v0;
    float v1 = sc * acc.y; v1 = (v1 >= 0.f) ? v1 : a * v1;
    float v2 = sc * acc.z; v2 = (v2 >= 0.f) ? v2 : a * v2;
    float v3 = sc * acc.w; v3 = (v3 >= 0.f) ? v3 : a * v3;

    float pv = fmaf(v0, v0, fmaf(v1, v1, fmaf(v2, v2, v3 * v3)));
    float m2 = red32(pv);
    float rc = fmaxf(sqrtf(m2), MINN);
    float te = tanhf(rc);
    float es = te / rc;
    float en = fmaxf(te, MINN);
    const float maxn = 1.0f - BALLEPS;
    float fsc = (en > maxn) ? (es * maxn / en) : es;

    float4 o = make_float4(fsc * v0, fsc * v1, fsc * v2, fsc * v3);
    ((float4*)out)[(size_t)n * 32 + tx] = o;
}

// ---------------------------------------------------------------------------
extern "C" void kernel_launch(void* const* d_in, const int* in_sizes, int n_in,
                              void* d_out, int out_size, void* d_ws, size_t ws_size,
                              hipStream_t stream)
{
    const float* x  = (const float*)d_in[0];
    const int*   ei = (const int*)  d_in[1];
    const float* ew = (const float*)d_in[2];
    const float* W  = (const float*)d_in[3];
    const float* b  = (const float*)d_in[4];
    const float* a  = (const float*)d_in[5];
    float* out = (float*)d_out;

    const int N = in_sizes[0] / D;
    const int E = in_sizes[1] / 2;

    // workspace carve-up (~31.2 MB)
    char* ws = (char*)d_ws;
    size_t HT_B   = (size_t)N * D * 2;          // fp16 h_t
    uint2* ht     = (uint2*)ws;
    int*   cnt    = (int*)(ws + HT_B);
    int*   ptr    = (int*)(ws + HT_B + (size_t)N * 4);
    int*   part   = (int*)(ws + HT_B + (size_t)N * 8);
    int2*  sorted = (int2*)(ws + HT_B + (size_t)N * 8 + 1024);

    int nc = (N + 1023) / 1024;   // scan chunks

    k_node_mfma<<<(N + 63) / 64, BLK, 0, stream>>>(x, W, b, ht, N);

    k_zero<<<(N + 255) / 256, 256, 0, stream>>>(cnt, N);
    k_hist<<<(E + 255) / 256, 256, 0, stream>>>(ei, cnt, E);
    k_scan1<<<nc, 256, 0, stream>>>(cnt, ptr, part, N);
    k_scan2<<<1, 256, 0, stream>>>(part, nc);
    k_scan3<<<(N + 255) / 256, 256, 0, stream>>>(ptr, part, N);
    k_scatter<<<(E + 255) / 256, 256, 0, stream>>>(ei, ew, ptr, sorted, E);

    k_agg_final<<<(N + 7) / 8, 256, 0, stream>>>(ht, ptr, sorted, a, out, N);
}